// Round 2
// baseline (1350.992 us; speedup 1.0000x reference)
//
#include <hip/hip_runtime.h>

constexpr int B = 512, S = 1024, IN = 32, H = 128;
constexpr int KTOT = IN + H;   // 160
constexpr int KSL = KTOT / 4;  // 40 k per slice

template <int CTRL>
__device__ __forceinline__ float dpp_qp(float v) {
  return __int_as_float(__builtin_amdgcn_update_dpp(
      0, __float_as_int(v), CTRL, 0xF, 0xF, true));
}
__device__ __forceinline__ float sigm(float v) {
  float e = __builtin_amdgcn_exp2f(-1.4426950408889634f * v);
  return __builtin_amdgcn_rcpf(1.0f + e);
}
__device__ __forceinline__ float tanh_(float v) {
  float e = __builtin_amdgcn_exp2f(-2.8853900817779268f * v);
  return 2.0f * __builtin_amdgcn_rcpf(1.0f + e) - 1.0f;
}

__global__ __launch_bounds__(512, 2)
void lstm_fused(const float* __restrict__ x, const float* __restrict__ Wih,
                const float* __restrict__ Whh, const float* __restrict__ bih,
                const float* __restrict__ bhh, const float* __restrict__ Wlin,
                const float* __restrict__ blin, float* __restrict__ out) {
  __shared__ alignas(16) float hxA[KTOT];  // batch b0: [x_t(32) | h(128)]
  __shared__ alignas(16) float hxB[KTOT];  // batch b0+1
  __shared__ float red[2 * H];

  const int tid = threadIdx.x;
  const int g = tid >> 2;  // hidden unit 0..127
  const int j = tid & 3;   // k-slice 0..3
  const int b0 = blockIdx.x * 2;

  // ---- weights into registers: 4 gate rows x 40 k = 160 VGPRs ----
  float w[4][KSL];
#pragma unroll
  for (int c = 0; c < 4; ++c) {
    const int n = c * H + g;
#pragma unroll
    for (int kk = 0; kk < KSL; ++kk) {
      const int k = KSL * j + kk;
      const float* p = (k < IN) ? (Wih + n * IN + k) : (Whh + n * H + (k - IN));
      w[c][kk] = *p;
    }
  }
  float bias[4];
#pragma unroll
  for (int c = 0; c < 4; ++c) bias[c] = bih[c * H + g] + bhh[c * H + g];

  // ---- init LDS: zero h part, stage x for s=0 ----
  if (tid < KTOT) { hxA[tid] = 0.0f; hxB[tid] = 0.0f; }
  __syncthreads();
  if (tid < 2 * IN) {
    const int b = tid >> 5, k = tid & 31;
    (b ? hxB : hxA)[k] = x[(size_t)(b0 + b) * (S * IN) + k];
  }
  __syncthreads();

  float cc0 = 0.f, cc1 = 0.f;   // cell state (valid on j==0 lanes)
  float oa0 = 0.f, oa1 = 0.f;   // fused output-linear accumulators
  const int xb = g >> 5, xk = g & 31;

  for (int s = 0; s < S; ++s) {
    // prefetch W_lin slice (this step) and x (next step) early
    float wl = 0.f, xn = 0.f;
    if (j == 0) wl = Wlin[s * H + g];
    const bool xload = (j == 1) && (g < 64) && (s + 1 < S);
    if (xload) xn = x[(size_t)(b0 + xb) * (S * IN) + (s + 1) * IN + xk];

    // ---- gate GEMM slice: acc[c][b] = sum_{k in slice} hx[b][k]*w[c][k] ----
    float acc[4][2];
#pragma unroll
    for (int c = 0; c < 4; ++c) { acc[c][0] = 0.f; acc[c][1] = 0.f; }
    const float4* pA = reinterpret_cast<const float4*>(hxA + KSL * j);
    const float4* pB = reinterpret_cast<const float4*>(hxB + KSL * j);
#pragma unroll
    for (int q = 0; q < KSL / 4; ++q) {
      const float4 va = pA[q];
      const float4 vb = pB[q];
      const float ea[4] = {va.x, va.y, va.z, va.w};
      const float eb[4] = {vb.x, vb.y, vb.z, vb.w};
#pragma unroll
      for (int u = 0; u < 4; ++u)
#pragma unroll
        for (int c = 0; c < 4; ++c) {
          acc[c][0] = fmaf(ea[u], w[c][4 * q + u], acc[c][0]);
          acc[c][1] = fmaf(eb[u], w[c][4 * q + u], acc[c][1]);
        }
    }
    // ---- quad butterfly reduce over k-slices (VALU DPP, no LDS) ----
#pragma unroll
    for (int c = 0; c < 4; ++c)
#pragma unroll
      for (int b = 0; b < 2; ++b) {
        float v = acc[c][b];
        v += dpp_qp<0xB1>(v);  // xor 1
        v += dpp_qp<0x4E>(v);  // xor 2
        acc[c][b] = v;
      }
    __syncthreads();  // gate reads of hx done; safe to overwrite hx
    if (j == 0) {
#pragma unroll
      for (int b = 0; b < 2; ++b) {
        const float gi = sigm(acc[0][b] + bias[0]);
        const float gf = sigm(acc[1][b] + bias[1]);
        const float gc = tanh_(acc[2][b] + bias[2]);
        const float go = sigm(acc[3][b] + bias[3]);
        float& cc = b ? cc1 : cc0;
        cc = gf * cc + gi * gc;
        const float h = go * tanh_(cc);
        (b ? hxB : hxA)[IN + g] = h;
        (b ? oa1 : oa0) += h * wl;
      }
    } else if (xload) {
      (xb ? hxB : hxA)[xk] = xn;  // stage x for step s+1
    }
    __syncthreads();  // hx for step s+1 ready
  }

  // ---- final reduce of fused linear ----
  if (j == 0) { red[2 * g] = oa0; red[2 * g + 1] = oa1; }
  __syncthreads();
  if (tid < 2) {
    float sum = blin[0];
    for (int k = 0; k < H; ++k) sum += red[2 * k + tid];
    out[b0 + tid] = sum;
  }
}

extern "C" void kernel_launch(void* const* d_in, const int* in_sizes, int n_in,
                              void* d_out, int out_size, void* d_ws, size_t ws_size,
                              hipStream_t stream) {
  const float* x    = (const float*)d_in[0];
  const float* Wih  = (const float*)d_in[1];
  const float* Whh  = (const float*)d_in[2];
  const float* bih  = (const float*)d_in[3];
  const float* bhh  = (const float*)d_in[4];
  const float* Wlin = (const float*)d_in[5];
  const float* blin = (const float*)d_in[6];
  float* outp = (float*)d_out;
  hipLaunchKernelGGL(lstm_fused, dim3(B / 2), dim3(512), 0, stream,
                     x, Wih, Whh, bih, bhh, Wlin, blin, outp);
}